// Round 6
// baseline (501.434 us; speedup 1.0000x reference)
//
#include <hip/hip_runtime.h>

#define N_NODES 100000
#define D_FEAT  128
#define N_EDGES 1600000
#define EPSBN   1e-5f
#define SLOPE   0.01f

#define NBUCK   782          // ceil(100000 / 128) dst-buckets (128 nodes each)
#define PBLK    256          // partition blocks
#define CHUNK   6250         // edges per partition block (256*6250 = 1.6M exact)
#define BCAPT   2560         // tmp capacity per bucket (mean 2046, 11 sigma)
#define CSTR    3072         // csr entries per bucket (<= BCAPT + 4*128)
#define NSPR    8            // BN-stat accumulator spread copies

typedef __attribute__((ext_vector_type(8))) short bf16x8;
typedef __attribute__((ext_vector_type(4))) float f32x4;
typedef unsigned short u16;
typedef unsigned int   u32;

__device__ __forceinline__ u16 f2bf(float f) {
    u32 x = __float_as_uint(f);
    u32 r = (x + 0x7fffu + ((x >> 16) & 1u)) >> 16;
    return (u16)r;
}
__device__ __forceinline__ float bf_lo(u32 w) { return __uint_as_float(w << 16); }
__device__ __forceinline__ float bf_hi(u32 w) { return __uint_as_float(w & 0xffff0000u); }

// ---------------- init + W swizzle (one kernel, 48 blocks) ----------------
// blocks 0..15:  pre-swizzle W1+W2 into MFMA B-fragment order (bf16):
//   frag t=(kc*8+nt)*64+lane holds 8 bf16 W[kc*32+(lane>>4)*8+j][nt*16+(lane&15)]
// blocks 16..47: zero stats (4096 f), zero-row of Hb, init bucket cursors.
__global__ void k_init(const float* __restrict__ W1, const float* __restrict__ W2,
                       u16* __restrict__ wz1, u16* __restrict__ wz2,
                       float* __restrict__ stats, u32* __restrict__ zrow,
                       int* __restrict__ gcur) {
    int blk = blockIdx.x, tid = threadIdx.x;
    if (blk < 16) {
        int t = blk * 256 + tid;             // 0..4095 over both W
        const float* W = (t < 2048) ? W1 : W2;
        u16* Wz = (t < 2048) ? wz1 : wz2;
        int tt = t & 2047;
        int lane = tt & 63, frag = tt >> 6;
        int nt = frag & 7, kc = frag >> 3;
        int n  = nt * 16 + (lane & 15);
        int kb = kc * 32 + (lane >> 4) * 8;
        u16 v[8];
#pragma unroll
        for (int j = 0; j < 8; ++j) v[j] = f2bf(W[(kb + j) * 128 + n]);
#pragma unroll
        for (int j = 0; j < 8; ++j) Wz[tt * 8 + j] = v[j];
    } else {
        int j = (blk - 16) * 256 + tid;      // 0..8191
        if (j < 4096) stats[j] = 0.f;
        if (j < 64) zrow[j] = 0u;
        if (j < NBUCK) gcur[j] = j * BCAPT;
    }
}

// ---------------- P1: fused hist + claim + scatter ----------------
// Per block: LDS histogram of its CHUNK, ONE global atomicAdd per (block,bucket)
// to claim a contiguous run in the bucket's fixed region, then scatter through
// LDS cursors. Each run (~8 edges) is written contiguously by one block in a
// burst -> 64B lines assemble in the store stream (the R3 k_part property).
__global__ __launch_bounds__(256) void k_part2(const int* __restrict__ src,
                                               const int* __restrict__ dst,
                                               int* __restrict__ gcur,
                                               u32* __restrict__ tmp) {
    __shared__ int hist[NBUCK];
    __shared__ int lcur[NBUCK];
    int tid = threadIdx.x, blk = blockIdx.x;
    for (int i = tid; i < NBUCK; i += 256) hist[i] = 0;
    __syncthreads();
    int e0 = blk * CHUNK;
    for (int e = e0 + tid; e < e0 + CHUNK; e += 256)
        atomicAdd(&hist[dst[e] >> 7], 1);
    __syncthreads();
    for (int i = tid; i < NBUCK; i += 256) {
        int c = hist[i];
        lcur[i] = c ? atomicAdd(&gcur[i], c) : 0;
    }
    __syncthreads();
    for (int e = e0 + tid; e < e0 + CHUNK; e += 256) {   // 2nd read is L2-hot
        int s = src[e], d = dst[e];
        int slot = atomicAdd(&lcur[d >> 7], 1);
        tmp[slot] = (u32)s | ((u32)(d & 127) << 20);
    }
}

// ---------------- P2: per-bucket padded-CSR build ----------------
// One block per bucket, range [b*BCAPT, gcur[b]). Count 128 node degrees, scan
// PADDED counts (self + pad-to-4) -> rows at fixed base b*CSTR:
//   row = [edges..., self, N_NODES-pads...]  (len multiple of 4, int4-aligned)
// meta[node] = { row_start_in_int4, rounds, bits(dinv), 0 }
__global__ __launch_bounds__(256) void k_bucket(const u32* __restrict__ tmp,
                                                const int* __restrict__ gcur,
                                                int4* __restrict__ meta,
                                                float* __restrict__ dinv,
                                                int* __restrict__ csr_src) {
    __shared__ int lcnt[128];
    __shared__ int sc[128];
    __shared__ int lcur[128];
    int tid = threadIdx.x, b = blockIdx.x;
    int lo = b * BCAPT, hi = gcur[b];
    int pbase = b * CSTR;                       // int4-aligned (CSTR%4==0)
    if (tid < 128) lcnt[tid] = 0;
    __syncthreads();
    for (int e = lo + tid; e < hi; e += 256)
        atomicAdd(&lcnt[tmp[e] >> 20], 1);
    __syncthreads();
    int c  = (tid < 128) ? lcnt[tid] : 0;
    int c4 = (c + 4) & ~3;                      // edges + self, rounded up to 4
    if (tid < 128) sc[tid] = c4;
    __syncthreads();
    for (int off = 1; off < 128; off <<= 1) {
        int add = (tid < 128 && tid >= off) ? sc[tid - off] : 0;
        __syncthreads();
        if (tid < 128) sc[tid] += add;
        __syncthreads();
    }
    if (tid < 128) {
        int node = (b << 7) + tid;
        int excl = pbase + sc[tid] - c4;
        lcur[tid] = excl;
        if (node < N_NODES) {
            float di = rsqrtf((float)(c + 1));
            dinv[node] = di;
            int4 m; m.x = excl >> 2; m.y = c4 >> 2; m.z = __float_as_int(di); m.w = 0;
            meta[node] = m;
            csr_src[excl + c] = node;           // self contribution (Hb already *dinv)
            for (int k = c + 1; k < c4; ++k) csr_src[excl + k] = N_NODES;  // zero row
        }
    }
    __syncthreads();
    for (int e = lo + tid; e < hi; e += 256) {
        u32 pk = tmp[e];
        int slot = atomicAdd(&lcur[pk >> 20], 1);
        csr_src[slot] = (int)(pk & 0xFFFFFu);
    }
}

// ---- GEMM: Hb[M x 128](bf16) = (act(A) @ W) * dinv[row]
//   ABF16: A is packed bf16 (u32 pairs, 64/row); else f32.
//   FUSE:  act = leaky(A*scale+shift); scale/shift from NSPR-spread BN sums.

template <bool FUSE, bool ABF16>
__global__ __launch_bounds__(256) void k_gemm(const void* __restrict__ Ap,
                                              const u16* __restrict__ Wz,
                                              const float* __restrict__ gsum,
                                              const float* __restrict__ gsq,
                                              const float* __restrict__ gam,
                                              const float* __restrict__ bet,
                                              const float* __restrict__ dinv,
                                              u16* __restrict__ Hb, int M) {
    __shared__ u16 wl[16384];  // 32 KB
    __shared__ float sLds[128], hLds[128];
    int tid = threadIdx.x;
    {
        const uint4* s4 = (const uint4*)Wz;
        uint4* d4 = (uint4*)wl;
        for (int i = tid; i < 2048; i += 256) d4[i] = s4[i];
    }
    if (FUSE && tid < 128) {
        float s = 0.f, s2 = 0.f;
#pragma unroll
        for (int k = 0; k < NSPR; ++k) { s += gsum[k * 128 + tid]; s2 += gsq[k * 128 + tid]; }
        float mean = s * (1.f / N_NODES);
        float var  = s2 * (1.f / N_NODES) - mean * mean;
        float rstd = rsqrtf(var + EPSBN);
        float sc = gam[tid] * rstd;
        sLds[tid] = sc;
        hLds[tid] = bet[tid] - mean * sc;
    }
    __syncthreads();
    int wave = tid >> 6, lane = tid & 63;
    long m0 = ((long)blockIdx.x * 4 + wave) * 16;
    if (m0 >= M) return;
    int mr = lane & 15, quad = lane >> 4;
    f32x4 acc[8] = {};
#pragma unroll
    for (int kc = 0; kc < 4; ++kc) {
        float av[8];
        if (ABF16) {
            const u32* arow = (const u32*)Ap + (size_t)(m0 + mr) * 64;
            uint4 aw = ((const uint4*)arow)[kc * 4 + quad];
            av[0] = bf_lo(aw.x); av[1] = bf_hi(aw.x);
            av[2] = bf_lo(aw.y); av[3] = bf_hi(aw.y);
            av[4] = bf_lo(aw.z); av[5] = bf_hi(aw.z);
            av[6] = bf_lo(aw.w); av[7] = bf_hi(aw.w);
        } else {
            const float* arow = (const float*)Ap + (size_t)(m0 + mr) * 128 + quad * 8;
            float4 a0 = *(const float4*)(arow + kc * 32);
            float4 a1 = *(const float4*)(arow + kc * 32 + 4);
            av[0] = a0.x; av[1] = a0.y; av[2] = a0.z; av[3] = a0.w;
            av[4] = a1.x; av[5] = a1.y; av[6] = a1.z; av[7] = a1.w;
        }
        if (FUSE) {
            int c = kc * 32 + quad * 8;
#pragma unroll
            for (int j = 0; j < 8; ++j) {
                float v = fmaf(av[j], sLds[c + j], hLds[c + j]);
                av[j] = v > 0.f ? v : v * SLOPE;
            }
        }
        bf16x8 af;
#pragma unroll
        for (int j = 0; j < 8; ++j) af[j] = (short)f2bf(av[j]);
        const u16* wb = wl + (kc * 4096 + lane * 8);  // fragment (kc,nt) at (kc*8+nt)*512
#pragma unroll
        for (int nt = 0; nt < 8; ++nt) {
            bf16x8 bf = *(const bf16x8*)(wb + nt * 512);
            acc[nt] = __builtin_amdgcn_mfma_f32_16x16x32_bf16(af, bf, acc[nt], 0, 0, 0);
        }
    }
    // C/D layout: col = lane&15, row = quad*4 + r ; scale row by dinv, store bf16
    float dr[4];
#pragma unroll
    for (int r = 0; r < 4; ++r) dr[r] = dinv[m0 + quad * 4 + r];
    u16* hb = Hb + (size_t)m0 * 128 + (lane & 15);
#pragma unroll
    for (int nt = 0; nt < 8; ++nt)
#pragma unroll
        for (int r = 0; r < 4; ++r)
            hb[(size_t)(quad * 4 + r) * 128 + nt * 16] = f2bf(acc[nt][r] * dr[r]);
}

// ---------------- aggregation + fused BN stats ----------------
// One wave per node, 4 groups of 16 lanes. Padded CSR rows (multiple of 4,
// self folded in, zero-row pads): group g handles int4 slots r = g, g+4, ...
// Per round: one broadcast int4 index load + 4 row gathers + adds.
// AGGb[d] = bf16( dinv[d] * sum_slots Hb[slot] )
// BN stats: block LDS-reduce of its 4 rows -> 256 atomicAdds into NSPR-spread
// global accumulators (per-line RMW rate / NSPR).

__device__ __forceinline__ void add8(float* acc, uint4 w) {
    acc[0] += bf_lo(w.x); acc[1] += bf_hi(w.x);
    acc[2] += bf_lo(w.y); acc[3] += bf_hi(w.y);
    acc[4] += bf_lo(w.z); acc[5] += bf_hi(w.z);
    acc[6] += bf_lo(w.w); acc[7] += bf_hi(w.w);
}

__global__ __launch_bounds__(256) void k_agg(const uint4* __restrict__ Hb4,
                                             const int4* __restrict__ meta,
                                             const int4* __restrict__ csr4,
                                             u32* __restrict__ AGGb,
                                             float* __restrict__ gsum,
                                             float* __restrict__ gsq) {
    __shared__ float bsum[128], bsq[128];
    int tid = threadIdx.x;
    int wave = tid >> 6, lane = tid & 63;
    if (tid < 128) { bsum[tid] = 0.f; bsq[tid] = 0.f; }
    __syncthreads();
    int node = blockIdx.x * 4 + wave;  // 25000*4 = 100000 exact
    int g = lane >> 4, f = lane & 15;
    int4 m = meta[node];               // wave-uniform 16B broadcast
    int s4 = m.x, rn = m.y;
    float di = __int_as_float(m.z);
    float acc[8] = {0.f, 0.f, 0.f, 0.f, 0.f, 0.f, 0.f, 0.f};
    for (int r = g; r < rn; r += 4) {
        int4 idx = csr4[s4 + r];       // 16 lanes same addr; 4 groups = 64B line
        uint4 a0 = Hb4[((size_t)idx.x << 4) + f];
        uint4 a1 = Hb4[((size_t)idx.y << 4) + f];
        uint4 a2 = Hb4[((size_t)idx.z << 4) + f];
        uint4 a3 = Hb4[((size_t)idx.w << 4) + f];
        add8(acc, a0); add8(acc, a1); add8(acc, a2); add8(acc, a3);
    }
#pragma unroll
    for (int i = 0; i < 8; ++i) {
        acc[i] += __shfl_xor(acc[i], 16);
        acc[i] += __shfl_xor(acc[i], 32);
    }
#pragma unroll
    for (int i = 0; i < 8; ++i) acc[i] *= di;
    if (g == 0) {                      // all groups hold the full sum; one writes
        u32 p0 = (u32)f2bf(acc[0]) | ((u32)f2bf(acc[1]) << 16);
        u32 p1 = (u32)f2bf(acc[2]) | ((u32)f2bf(acc[3]) << 16);
        u32 p2 = (u32)f2bf(acc[4]) | ((u32)f2bf(acc[5]) << 16);
        u32 p3 = (u32)f2bf(acc[6]) | ((u32)f2bf(acc[7]) << 16);
        uint4 o; o.x = p0; o.y = p1; o.z = p2; o.w = p3;
        ((uint4*)(AGGb + (size_t)node * 64))[f] = o;
#pragma unroll
        for (int j = 0; j < 8; ++j) {
            float v = acc[j];
            atomicAdd(&bsum[f * 8 + j], v);
            atomicAdd(&bsq[f * 8 + j], v * v);
        }
    }
    __syncthreads();
    if (tid < 128) {
        int o = (blockIdx.x & (NSPR - 1)) * 128 + tid;
        atomicAdd(&gsum[o], bsum[tid]);
        atomicAdd(&gsq[o],  bsq[tid]);
    }
}

// out = leaky(agg*scale + shift + x), f32 out; AGG bf16-packed, BN finalize
// inline from NSPR-spread sums. Grid-stride over 1.6M uint4.
__global__ __launch_bounds__(256) void k_ew2(const uint4* __restrict__ AGGb4,
                                             const float* __restrict__ gsum,
                                             const float* __restrict__ gsq,
                                             const float* __restrict__ gam,
                                             const float* __restrict__ bet,
                                             const float4* __restrict__ x4,
                                             float4* __restrict__ out4) {
    __shared__ float sLds[128], hLds[128];
    int tid = threadIdx.x;
    if (tid < 128) {
        float s = 0.f, s2 = 0.f;
#pragma unroll
        for (int k = 0; k < NSPR; ++k) { s += gsum[k * 128 + tid]; s2 += gsq[k * 128 + tid]; }
        float mean = s * (1.f / N_NODES);
        float var  = s2 * (1.f / N_NODES) - mean * mean;
        float rstd = rsqrtf(var + EPSBN);
        float sc = gam[tid] * rstd;
        sLds[tid] = sc;
        hLds[tid] = bet[tid] - mean * sc;
    }
    __syncthreads();
    for (long i = (long)blockIdx.x * 256 + tid; i < (long)N_NODES * 16; i += 2048 * 256) {
        int c8 = ((int)i & 15) * 8;
        uint4 w = AGGb4[i];
        float4 xa = x4[2 * i], xb = x4[2 * i + 1];
        float4 oa, ob;
        float v;
        v = fmaf(bf_lo(w.x), sLds[c8+0], hLds[c8+0]) + xa.x; oa.x = v > 0.f ? v : v * SLOPE;
        v = fmaf(bf_hi(w.x), sLds[c8+1], hLds[c8+1]) + xa.y; oa.y = v > 0.f ? v : v * SLOPE;
        v = fmaf(bf_lo(w.y), sLds[c8+2], hLds[c8+2]) + xa.z; oa.z = v > 0.f ? v : v * SLOPE;
        v = fmaf(bf_hi(w.y), sLds[c8+3], hLds[c8+3]) + xa.w; oa.w = v > 0.f ? v : v * SLOPE;
        v = fmaf(bf_lo(w.z), sLds[c8+4], hLds[c8+4]) + xb.x; ob.x = v > 0.f ? v : v * SLOPE;
        v = fmaf(bf_hi(w.z), sLds[c8+5], hLds[c8+5]) + xb.y; ob.y = v > 0.f ? v : v * SLOPE;
        v = fmaf(bf_lo(w.w), sLds[c8+6], hLds[c8+6]) + xb.z; ob.z = v > 0.f ? v : v * SLOPE;
        v = fmaf(bf_hi(w.w), sLds[c8+7], hLds[c8+7]) + xb.w; ob.w = v > 0.f ? v : v * SLOPE;
        out4[2 * i]     = oa;
        out4[2 * i + 1] = ob;
    }
}

// ---------------- launch ----------------

extern "C" void kernel_launch(void* const* d_in, const int* in_sizes, int n_in,
                              void* d_out, int out_size, void* d_ws, size_t ws_size,
                              hipStream_t stream) {
    const float* x   = (const float*)d_in[0];
    const int*   ei  = (const int*)d_in[1];
    const float* W1  = (const float*)d_in[2];
    const float* g1  = (const float*)d_in[4];
    const float* be1 = (const float*)d_in[5];
    const float* W2  = (const float*)d_in[6];
    const float* g2  = (const float*)d_in[8];
    const float* be2 = (const float*)d_in[9];
    const int* src = ei;
    const int* dst = ei + N_EDGES;

    float* out = (float*)d_out;
    u16*   Hb  = (u16*)d_out;  // bf16 H (rows 0..N_NODES incl zero-row) lives in d_out

    char* p = (char*)d_ws;
    u32*   aggb    = (u32*)p;   p += (size_t)N_NODES * 64 * 4;   // 25.6 MB bf16 AGG
    u32*   tmp     = aggb;      // tmp (NBUCK*BCAPT*4 = 8.0 MB) overlays aggb:
                                // dead before first k_agg write
    int*   csr_src = (int*)p;   p += (size_t)NBUCK * CSTR * 4;   // 9.6 MB padded CSR
    int*   gcur    = (int*)p;   p += 1024 * 4;                   // bucket cursors
    int4*  meta    = (int4*)p;  p += (size_t)100096 * 16;        // 1.6 MB
    float* dinv    = (float*)p; p += (size_t)100096 * 4;
    float* stats   = (float*)p; p += 4096 * 4;                   // 4x 8-spread arrays
    u16*   wz1     = (u16*)p;   p += 16384 * 2;
    u16*   wz2     = (u16*)p;   p += 16384 * 2;

    float* gs1 = stats,        *gq1 = stats + 1024;
    float* gs2 = stats + 2048, *gq2 = stats + 3072;

    // setup: init/swz -> fused hist+claim+scatter -> per-bucket padded-CSR build
    k_init<<<48, 256, 0, stream>>>(W1, W2, wz1, wz2, stats,
                                   (u32*)Hb + (size_t)N_NODES * 64, gcur);
    k_part2<<<PBLK, 256, 0, stream>>>(src, dst, gcur, tmp);
    k_bucket<<<NBUCK, 256, 0, stream>>>(tmp, gcur, meta, dinv, csr_src);

    // layer 1:  Hb1 = (x@W1)*dinv -> d_out (bf16),  AGG1 -> aggb (+BN1 stats)
    k_gemm<false, false><<<1563, 256, 0, stream>>>(x, wz1, nullptr, nullptr, nullptr,
                                                   nullptr, dinv, Hb, N_NODES);
    k_agg<<<25000, 256, 0, stream>>>((const uint4*)Hb, meta, (const int4*)csr_src,
                                     aggb, gs1, gq1);

    // layer 2:  Hb2 = (leaky(BN1(AGG1))@W2)*dinv -> d_out;  AGG2 -> aggb (+BN2 stats)
    k_gemm<true, true><<<1563, 256, 0, stream>>>(aggb, wz2, gs1, gq1, g1, be1,
                                                 dinv, Hb, N_NODES);
    k_agg<<<25000, 256, 0, stream>>>((const uint4*)Hb, meta, (const int4*)csr_src,
                                     aggb, gs2, gq2);

    // epilogue: BN2 finalize inline + residual + leaky
    k_ew2<<<2048, 256, 0, stream>>>((const uint4*)aggb, gs2, gq2, g2, be2,
                                    (const float4*)x, (float4*)out);
}

// Round 7
// 352.865 us; speedup vs baseline: 1.4210x; 1.4210x over previous
//
#include <hip/hip_runtime.h>

#define N_NODES 100000
#define D_FEAT  128
#define N_EDGES 1600000
#define EPSBN   1e-5f
#define SLOPE   0.01f

#define NBUCK   782          // ceil(100000 / 128) dst-buckets (128 nodes each)
#define PBLK    256          // partition blocks
#define CHUNK   6250         // edges per partition block (256*6250 = 1.6M exact)
#define BCAPT   2560         // tmp capacity per bucket (mean 2046, 11 sigma)
#define CSTR    3072         // csr entries per bucket (<= BCAPT + 4*128)

typedef __attribute__((ext_vector_type(8))) short bf16x8;
typedef __attribute__((ext_vector_type(4))) float f32x4;
typedef unsigned short u16;
typedef unsigned int   u32;

__device__ __forceinline__ u16 f2bf(float f) {
    u32 x = __float_as_uint(f);
    u32 r = (x + 0x7fffu + ((x >> 16) & 1u)) >> 16;
    return (u16)r;
}
__device__ __forceinline__ float bf_lo(u32 w) { return __uint_as_float(w << 16); }
__device__ __forceinline__ float bf_hi(u32 w) { return __uint_as_float(w & 0xffff0000u); }

// ---------------- init + W swizzle (one kernel, 20 blocks) ----------------
// blocks 0..15:  pre-swizzle W1+W2 into MFMA B-fragment order (bf16):
//   frag t=(kc*8+nt)*64+lane holds 8 bf16 W[kc*32+(lane>>4)*8+j][nt*16+(lane&15)]
// blocks 16..19: zero stats (1024 f), zero-row of Hb, init bucket cursors.
__global__ void k_init(const float* __restrict__ W1, const float* __restrict__ W2,
                       u16* __restrict__ wz1, u16* __restrict__ wz2,
                       float* __restrict__ stats, u32* __restrict__ zrow,
                       int* __restrict__ gcur) {
    int blk = blockIdx.x, tid = threadIdx.x;
    if (blk < 16) {
        int t = blk * 256 + tid;             // 0..4095 over both W
        const float* W = (t < 2048) ? W1 : W2;
        u16* Wz = (t < 2048) ? wz1 : wz2;
        int tt = t & 2047;
        int lane = tt & 63, frag = tt >> 6;
        int nt = frag & 7, kc = frag >> 3;
        int n  = nt * 16 + (lane & 15);
        int kb = kc * 32 + (lane >> 4) * 8;
        u16 v[8];
#pragma unroll
        for (int j = 0; j < 8; ++j) v[j] = f2bf(W[(kb + j) * 128 + n]);
#pragma unroll
        for (int j = 0; j < 8; ++j) Wz[tt * 8 + j] = v[j];
    } else {
        int j = (blk - 16) * 256 + tid;      // 0..1023
        if (j < 1024) stats[j] = 0.f;
        if (j < 64) zrow[j] = 0u;
        if (j < NBUCK) gcur[j] = j * BCAPT;
    }
}

// ---------------- P1: fused hist + claim + scatter ----------------
// Per block: LDS histogram of its CHUNK, ONE global atomicAdd per (block,bucket)
// to claim a contiguous run in the bucket's fixed region, then scatter through
// LDS cursors. Each run (~8 edges) is written contiguously by one block in a
// burst -> 64B lines assemble in the store stream.
__global__ __launch_bounds__(256) void k_part2(const int* __restrict__ src,
                                               const int* __restrict__ dst,
                                               int* __restrict__ gcur,
                                               u32* __restrict__ tmp) {
    __shared__ int hist[NBUCK];
    __shared__ int lcur[NBUCK];
    int tid = threadIdx.x, blk = blockIdx.x;
    for (int i = tid; i < NBUCK; i += 256) hist[i] = 0;
    __syncthreads();
    int e0 = blk * CHUNK;
    for (int e = e0 + tid; e < e0 + CHUNK; e += 256)
        atomicAdd(&hist[dst[e] >> 7], 1);
    __syncthreads();
    for (int i = tid; i < NBUCK; i += 256) {
        int c = hist[i];
        lcur[i] = c ? atomicAdd(&gcur[i], c) : 0;
    }
    __syncthreads();
    for (int e = e0 + tid; e < e0 + CHUNK; e += 256) {   // 2nd read is L2-hot
        int s = src[e], d = dst[e];
        int slot = atomicAdd(&lcur[d >> 7], 1);
        tmp[slot] = (u32)s | ((u32)(d & 127) << 20);
    }
}

// ---------------- P2: per-bucket padded-CSR build ----------------
// One block per bucket, range [b*BCAPT, gcur[b]). Count 128 node degrees, scan
// PADDED counts (self + pad-to-4) -> rows at fixed base b*CSTR:
//   row = [edges..., self, N_NODES-pads...]  (len multiple of 4, int4-aligned)
// meta[node] = { row_start_in_int4, rounds, bits(dinv), 0 }
__global__ __launch_bounds__(256) void k_bucket(const u32* __restrict__ tmp,
                                                const int* __restrict__ gcur,
                                                int4* __restrict__ meta,
                                                float* __restrict__ dinv,
                                                int* __restrict__ csr_src) {
    __shared__ int lcnt[128];
    __shared__ int sc[128];
    __shared__ int lcur[128];
    int tid = threadIdx.x, b = blockIdx.x;
    int lo = b * BCAPT, hi = gcur[b];
    int pbase = b * CSTR;                       // int4-aligned (CSTR%4==0)
    if (tid < 128) lcnt[tid] = 0;
    __syncthreads();
    for (int e = lo + tid; e < hi; e += 256)
        atomicAdd(&lcnt[tmp[e] >> 20], 1);
    __syncthreads();
    int c  = (tid < 128) ? lcnt[tid] : 0;
    int c4 = (c + 4) & ~3;                      // edges + self, rounded up to 4
    if (tid < 128) sc[tid] = c4;
    __syncthreads();
    for (int off = 1; off < 128; off <<= 1) {
        int add = (tid < 128 && tid >= off) ? sc[tid - off] : 0;
        __syncthreads();
        if (tid < 128) sc[tid] += add;
        __syncthreads();
    }
    if (tid < 128) {
        int node = (b << 7) + tid;
        int excl = pbase + sc[tid] - c4;
        lcur[tid] = excl;
        if (node < N_NODES) {
            float di = rsqrtf((float)(c + 1));
            dinv[node] = di;
            int4 m; m.x = excl >> 2; m.y = c4 >> 2; m.z = __float_as_int(di); m.w = 0;
            meta[node] = m;
            csr_src[excl + c] = node;           // self contribution (Hb already *dinv)
            for (int k = c + 1; k < c4; ++k) csr_src[excl + k] = N_NODES;  // zero row
        }
    }
    __syncthreads();
    for (int e = lo + tid; e < hi; e += 256) {
        u32 pk = tmp[e];
        int slot = atomicAdd(&lcur[pk >> 20], 1);
        csr_src[slot] = (int)(pk & 0xFFFFFu);
    }
}

// ---- GEMM: Hb[M x 128](bf16) = (act(A) @ W) * dinv[row]
//   ABF16: A is packed bf16 (u32 pairs, 64/row); else f32.
//   FUSE:  act = leaky(A*scale+shift), scale/shift computed from BN sums in prologue

template <bool FUSE, bool ABF16>
__global__ __launch_bounds__(256) void k_gemm(const void* __restrict__ Ap,
                                              const u16* __restrict__ Wz,
                                              const float* __restrict__ sums,
                                              const float* __restrict__ sumsq,
                                              const float* __restrict__ gam,
                                              const float* __restrict__ bet,
                                              const float* __restrict__ dinv,
                                              u16* __restrict__ Hb, int M) {
    __shared__ u16 wl[16384];  // 32 KB
    __shared__ float sLds[128], hLds[128];
    int tid = threadIdx.x;
    {
        const uint4* s4 = (const uint4*)Wz;
        uint4* d4 = (uint4*)wl;
        for (int i = tid; i < 2048; i += 256) d4[i] = s4[i];
    }
    if (FUSE && tid < 128) {
        float mean = sums[tid] * (1.f / N_NODES);
        float var  = sumsq[tid] * (1.f / N_NODES) - mean * mean;
        float rstd = rsqrtf(var + EPSBN);
        float sc = gam[tid] * rstd;
        sLds[tid] = sc;
        hLds[tid] = bet[tid] - mean * sc;
    }
    __syncthreads();
    int wave = tid >> 6, lane = tid & 63;
    long m0 = ((long)blockIdx.x * 4 + wave) * 16;
    if (m0 >= M) return;
    int mr = lane & 15, quad = lane >> 4;
    f32x4 acc[8] = {};
#pragma unroll
    for (int kc = 0; kc < 4; ++kc) {
        float av[8];
        if (ABF16) {
            const u32* arow = (const u32*)Ap + (size_t)(m0 + mr) * 64;
            uint4 aw = ((const uint4*)arow)[kc * 4 + quad];
            av[0] = bf_lo(aw.x); av[1] = bf_hi(aw.x);
            av[2] = bf_lo(aw.y); av[3] = bf_hi(aw.y);
            av[4] = bf_lo(aw.z); av[5] = bf_hi(aw.z);
            av[6] = bf_lo(aw.w); av[7] = bf_hi(aw.w);
        } else {
            const float* arow = (const float*)Ap + (size_t)(m0 + mr) * 128 + quad * 8;
            float4 a0 = *(const float4*)(arow + kc * 32);
            float4 a1 = *(const float4*)(arow + kc * 32 + 4);
            av[0] = a0.x; av[1] = a0.y; av[2] = a0.z; av[3] = a0.w;
            av[4] = a1.x; av[5] = a1.y; av[6] = a1.z; av[7] = a1.w;
        }
        if (FUSE) {
            int c = kc * 32 + quad * 8;
#pragma unroll
            for (int j = 0; j < 8; ++j) {
                float v = fmaf(av[j], sLds[c + j], hLds[c + j]);
                av[j] = v > 0.f ? v : v * SLOPE;
            }
        }
        bf16x8 af;
#pragma unroll
        for (int j = 0; j < 8; ++j) af[j] = (short)f2bf(av[j]);
        const u16* wb = wl + (kc * 4096 + lane * 8);  // fragment (kc,nt) at (kc*8+nt)*512
#pragma unroll
        for (int nt = 0; nt < 8; ++nt) {
            bf16x8 bf = *(const bf16x8*)(wb + nt * 512);
            acc[nt] = __builtin_amdgcn_mfma_f32_16x16x32_bf16(af, bf, acc[nt], 0, 0, 0);
        }
    }
    // C/D layout: col = lane&15, row = quad*4 + r ; scale row by dinv, store bf16
    float dr[4];
#pragma unroll
    for (int r = 0; r < 4; ++r) dr[r] = dinv[m0 + quad * 4 + r];
    u16* hb = Hb + (size_t)m0 * 128 + (lane & 15);
#pragma unroll
    for (int nt = 0; nt < 8; ++nt)
#pragma unroll
        for (int r = 0; r < 4; ++r)
            hb[(size_t)(quad * 4 + r) * 128 + nt * 16] = f2bf(acc[nt][r] * dr[r]);
}

// ---------------- aggregation ----------------
// One wave per node, 4 groups of 16 lanes. Padded CSR rows (multiple of 4,
// self folded in, zero-row pads): group g handles int4 slots r = g, g+4, ...
// Per round: one broadcast int4 index load + 4 row gathers + adds. No shfl,
// no tail masking, no weighted path.
// AGGb[d] = bf16( dinv[d] * sum_slots Hb[slot] )

__device__ __forceinline__ void add8(float* acc, uint4 w) {
    acc[0] += bf_lo(w.x); acc[1] += bf_hi(w.x);
    acc[2] += bf_lo(w.y); acc[3] += bf_hi(w.y);
    acc[4] += bf_lo(w.z); acc[5] += bf_hi(w.z);
    acc[6] += bf_lo(w.w); acc[7] += bf_hi(w.w);
}

__global__ __launch_bounds__(256) void k_agg(const uint4* __restrict__ Hb4,
                                             const int4* __restrict__ meta,
                                             const int4* __restrict__ csr4,
                                             u32* __restrict__ AGGb) {
    int wave = threadIdx.x >> 6, lane = threadIdx.x & 63;
    int node = blockIdx.x * 4 + wave;  // 25000*4 = 100000 exact
    int g = lane >> 4, f = lane & 15;
    int4 m = meta[node];               // wave-uniform 16B broadcast
    int s4 = m.x, rn = m.y;
    float di = __int_as_float(m.z);
    float acc[8] = {0.f, 0.f, 0.f, 0.f, 0.f, 0.f, 0.f, 0.f};
    for (int r = g; r < rn; r += 4) {
        int4 idx = csr4[s4 + r];       // 16 lanes same addr; 4 groups = 64B line
        uint4 a0 = Hb4[((size_t)idx.x << 4) + f];
        uint4 a1 = Hb4[((size_t)idx.y << 4) + f];
        uint4 a2 = Hb4[((size_t)idx.z << 4) + f];
        uint4 a3 = Hb4[((size_t)idx.w << 4) + f];
        add8(acc, a0); add8(acc, a1); add8(acc, a2); add8(acc, a3);
    }
#pragma unroll
    for (int i = 0; i < 8; ++i) {
        acc[i] += __shfl_xor(acc[i], 16);
        acc[i] += __shfl_xor(acc[i], 32);
    }
#pragma unroll
    for (int i = 0; i < 8; ++i) acc[i] *= di;
    if (g == 0) {                      // all groups hold the full sum; one writes
        u32 p0 = (u32)f2bf(acc[0]) | ((u32)f2bf(acc[1]) << 16);
        u32 p1 = (u32)f2bf(acc[2]) | ((u32)f2bf(acc[3]) << 16);
        u32 p2 = (u32)f2bf(acc[4]) | ((u32)f2bf(acc[5]) << 16);
        u32 p3 = (u32)f2bf(acc[6]) | ((u32)f2bf(acc[7]) << 16);
        uint4 o; o.x = p0; o.y = p1; o.z = p2; o.w = p3;
        ((uint4*)(AGGb + (size_t)node * 64))[f] = o;
    }
}

// ---------------- batch norm (bf16 AGG input) ----------------

__global__ void k_bnstats(const u32* __restrict__ AGGb, float* __restrict__ sums,
                          float* __restrict__ sumsq) {
    __shared__ float red[256];
    int col  = threadIdx.x & 127;
    int half = threadIdx.x >> 7;
    int odd  = col & 1, c2 = col >> 1;
    long r0 = (long)blockIdx.x * 200 + half;  // 500 blocks * 200 rows = 100000
    float s = 0.f, s2 = 0.f;
    for (int k = 0; k < 200; k += 2) {
        u32 w = AGGb[(r0 + k) * 64 + c2];
        float v = odd ? bf_hi(w) : bf_lo(w);
        s += v;
        s2 = fmaf(v, v, s2);
    }
    red[threadIdx.x] = s; __syncthreads();
    if (threadIdx.x < 128) atomicAdd(&sums[col], red[threadIdx.x] + red[threadIdx.x + 128]);
    __syncthreads();
    red[threadIdx.x] = s2; __syncthreads();
    if (threadIdx.x < 128) atomicAdd(&sumsq[col], red[threadIdx.x] + red[threadIdx.x + 128]);
}

// out = leaky(agg*scale + shift + x), f32 out; AGG bf16-packed, BN finalize
// inline. Grid-stride over 1.6M uint4.
__global__ __launch_bounds__(256) void k_ew2(const uint4* __restrict__ AGGb4,
                                             const float* __restrict__ sums,
                                             const float* __restrict__ sumsq,
                                             const float* __restrict__ gam,
                                             const float* __restrict__ bet,
                                             const float4* __restrict__ x4,
                                             float4* __restrict__ out4) {
    __shared__ float sLds[128], hLds[128];
    int tid = threadIdx.x;
    if (tid < 128) {
        float mean = sums[tid] * (1.f / N_NODES);
        float var  = sumsq[tid] * (1.f / N_NODES) - mean * mean;
        float rstd = rsqrtf(var + EPSBN);
        float sc = gam[tid] * rstd;
        sLds[tid] = sc;
        hLds[tid] = bet[tid] - mean * sc;
    }
    __syncthreads();
    for (long i = (long)blockIdx.x * 256 + tid; i < (long)N_NODES * 16; i += 2048 * 256) {
        int c8 = ((int)i & 15) * 8;
        uint4 w = AGGb4[i];
        float4 xa = x4[2 * i], xb = x4[2 * i + 1];
        float4 oa, ob;
        float v;
        v = fmaf(bf_lo(w.x), sLds[c8+0], hLds[c8+0]) + xa.x; oa.x = v > 0.f ? v : v * SLOPE;
        v = fmaf(bf_hi(w.x), sLds[c8+1], hLds[c8+1]) + xa.y; oa.y = v > 0.f ? v : v * SLOPE;
        v = fmaf(bf_lo(w.y), sLds[c8+2], hLds[c8+2]) + xa.z; oa.z = v > 0.f ? v : v * SLOPE;
        v = fmaf(bf_hi(w.y), sLds[c8+3], hLds[c8+3]) + xa.w; oa.w = v > 0.f ? v : v * SLOPE;
        v = fmaf(bf_lo(w.z), sLds[c8+4], hLds[c8+4]) + xb.x; ob.x = v > 0.f ? v : v * SLOPE;
        v = fmaf(bf_hi(w.z), sLds[c8+5], hLds[c8+5]) + xb.y; ob.y = v > 0.f ? v : v * SLOPE;
        v = fmaf(bf_lo(w.w), sLds[c8+6], hLds[c8+6]) + xb.z; ob.z = v > 0.f ? v : v * SLOPE;
        v = fmaf(bf_hi(w.w), sLds[c8+7], hLds[c8+7]) + xb.w; ob.w = v > 0.f ? v : v * SLOPE;
        out4[2 * i]     = oa;
        out4[2 * i + 1] = ob;
    }
}

// ---------------- launch ----------------

extern "C" void kernel_launch(void* const* d_in, const int* in_sizes, int n_in,
                              void* d_out, int out_size, void* d_ws, size_t ws_size,
                              hipStream_t stream) {
    const float* x   = (const float*)d_in[0];
    const int*   ei  = (const int*)d_in[1];
    const float* W1  = (const float*)d_in[2];
    const float* g1  = (const float*)d_in[4];
    const float* be1 = (const float*)d_in[5];
    const float* W2  = (const float*)d_in[6];
    const float* g2  = (const float*)d_in[8];
    const float* be2 = (const float*)d_in[9];
    const int* src = ei;
    const int* dst = ei + N_EDGES;

    float* out = (float*)d_out;
    u16*   Hb  = (u16*)d_out;  // bf16 H (rows 0..N_NODES incl zero-row) lives in d_out

    char* p = (char*)d_ws;
    u32*   aggb    = (u32*)p;   p += (size_t)N_NODES * 64 * 4;   // 25.6 MB bf16 AGG
    u32*   tmp     = aggb;      // tmp (NBUCK*BCAPT*4 = 8.0 MB) overlays aggb:
                                // dead before first k_agg write
    int*   csr_src = (int*)p;   p += (size_t)NBUCK * CSTR * 4;   // 9.6 MB padded CSR
    int*   gcur    = (int*)p;   p += 1024 * 4;                   // bucket cursors
    int4*  meta    = (int4*)p;  p += (size_t)100096 * 16;        // 1.6 MB
    float* dinv    = (float*)p; p += (size_t)100096 * 4;
    float* stats   = (float*)p; p += 1024 * 4;
    u16*   wz1     = (u16*)p;   p += 16384 * 2;
    u16*   wz2     = (u16*)p;   p += 16384 * 2;

    float* sums1 = stats,       *sq1 = stats + 128;
    float* sums2 = stats + 512, *sq2 = stats + 640;

    // setup: init/swz -> fused hist+claim+scatter -> per-bucket padded-CSR build
    k_init<<<20, 256, 0, stream>>>(W1, W2, wz1, wz2, stats,
                                   (u32*)Hb + (size_t)N_NODES * 64, gcur);
    k_part2<<<PBLK, 256, 0, stream>>>(src, dst, gcur, tmp);
    k_bucket<<<NBUCK, 256, 0, stream>>>(tmp, gcur, meta, dinv, csr_src);

    // layer 1:  Hb1 = (x@W1)*dinv -> d_out (bf16),  AGG1(bf16) -> aggb
    k_gemm<false, false><<<1563, 256, 0, stream>>>(x, wz1, nullptr, nullptr, nullptr,
                                                   nullptr, dinv, Hb, N_NODES);
    k_agg<<<25000, 256, 0, stream>>>((const uint4*)Hb, meta, (const int4*)csr_src, aggb);
    k_bnstats<<<500, 256, 0, stream>>>(aggb, sums1, sq1);

    // layer 2:  Hb2 = (leaky(BN1(AGG1))@W2)*dinv -> d_out;  AGG2(bf16) -> aggb
    k_gemm<true, true><<<1563, 256, 0, stream>>>(aggb, wz2, sums1, sq1, g1, be1,
                                                 dinv, Hb, N_NODES);
    k_agg<<<25000, 256, 0, stream>>>((const uint4*)Hb, meta, (const int4*)csr_src, aggb);
    k_bnstats<<<500, 256, 0, stream>>>(aggb, sums2, sq2);

    // epilogue: BN2 finalize inline + residual + leaky
    k_ew2<<<2048, 256, 0, stream>>>((const uint4*)aggb, sums2, sq2, g2, be2,
                                    (const float4*)x, (float4*)out);
}

// Round 8
// 326.107 us; speedup vs baseline: 1.5376x; 1.0821x over previous
//
#include <hip/hip_runtime.h>

#define N_NODES 100000
#define D_FEAT  128
#define N_EDGES 1600000
#define EPSBN   1e-5f
#define SLOPE   0.01f

#define NBUCK   782          // ceil(100000 / 128) dst-buckets (128 nodes each)
#define PBLK    256          // partition blocks
#define CHUNK   6250         // edges per partition block (256*6250 = 1.6M exact)
#define BCAPT   2560         // tmp capacity per bucket (mean 2046, 11 sigma)
#define CSTR    3072         // csr entries per bucket (<= BCAPT + 4*128)
#define NSPR    16           // BN-stat accumulator spread copies
#define BNB     512          // bnstats blocks

typedef __attribute__((ext_vector_type(8))) short bf16x8;
typedef __attribute__((ext_vector_type(4))) float f32x4;
typedef unsigned short u16;
typedef unsigned int   u32;

__device__ __forceinline__ u16 f2bf(float f) {
    u32 x = __float_as_uint(f);
    u32 r = (x + 0x7fffu + ((x >> 16) & 1u)) >> 16;
    return (u16)r;
}
__device__ __forceinline__ float bf_lo(u32 w) { return __uint_as_float(w << 16); }
__device__ __forceinline__ float bf_hi(u32 w) { return __uint_as_float(w & 0xffff0000u); }

// ---------------- init + W swizzle (one kernel, 48 blocks) ----------------
// blocks 0..15:  pre-swizzle W1+W2 into MFMA B-fragment order (bf16):
//   frag t=(kc*8+nt)*64+lane holds 8 bf16 W[kc*32+(lane>>4)*8+j][nt*16+(lane&15)]
// blocks 16..47: zero stats (8192 f = 4x 16-spread arrays), zero-row of Hb,
//                zero bucket cursors.
__global__ void k_init(const float* __restrict__ W1, const float* __restrict__ W2,
                       u16* __restrict__ wz1, u16* __restrict__ wz2,
                       float* __restrict__ stats, u32* __restrict__ zrow,
                       int* __restrict__ gcur) {
    int blk = blockIdx.x, tid = threadIdx.x;
    if (blk < 16) {
        int t = blk * 256 + tid;             // 0..4095 over both W
        const float* W = (t < 2048) ? W1 : W2;
        u16* Wz = (t < 2048) ? wz1 : wz2;
        int tt = t & 2047;
        int lane = tt & 63, frag = tt >> 6;
        int nt = frag & 7, kc = frag >> 3;
        int n  = nt * 16 + (lane & 15);
        int kb = kc * 32 + (lane >> 4) * 8;
        u16 v[8];
#pragma unroll
        for (int j = 0; j < 8; ++j) v[j] = f2bf(W[(kb + j) * 128 + n]);
#pragma unroll
        for (int j = 0; j < 8; ++j) Wz[tt * 8 + j] = v[j];
    } else {
        int j = (blk - 16) * 256 + tid;      // 0..8191
        if (j < 8192) stats[j] = 0.f;
        if (j < 64) zrow[j] = 0u;
        if (j < NBUCK) gcur[j] = 0;
    }
}

// ---------------- P1: fused hist + claim + scatter ----------------
// Per block: LDS histogram of its CHUNK, ONE global atomicAdd per (block,bucket)
// to claim a contiguous run in the bucket's fixed region, then scatter through
// LDS cursors. Each run (~8 edges) is written contiguously by one block in a
// burst -> 64B lines assemble in the store stream.
__global__ __launch_bounds__(256) void k_part2(const int* __restrict__ src,
                                               const int* __restrict__ dst,
                                               int* __restrict__ gcur,
                                               u32* __restrict__ tmp) {
    __shared__ int hist[NBUCK];
    __shared__ int lcur[NBUCK];
    int tid = threadIdx.x, blk = blockIdx.x;
    for (int i = tid; i < NBUCK; i += 256) hist[i] = 0;
    __syncthreads();
    int e0 = blk * CHUNK;
    for (int e = e0 + tid; e < e0 + CHUNK; e += 256)
        atomicAdd(&hist[dst[e] >> 7], 1);
    __syncthreads();
    for (int i = tid; i < NBUCK; i += 256) {
        int c = hist[i];
        lcur[i] = i * BCAPT + (c ? atomicAdd(&gcur[i], c) : 0);
    }
    __syncthreads();
    for (int e = e0 + tid; e < e0 + CHUNK; e += 256) {   // 2nd read is L2-hot
        int s = src[e], d = dst[e];
        int slot = atomicAdd(&lcur[d >> 7], 1);
        tmp[slot] = (u32)s | ((u32)(d & 127) << 20);
    }
}

// ---------------- P2: per-bucket padded-CSR build ----------------
// One block per bucket, range [b*BCAPT, b*BCAPT + gcur[b]). Count 128 node
// degrees, scan PADDED counts (self + pad-to-4) -> rows at fixed base b*CSTR:
//   row = [edges..., self, N_NODES-pads...]  (len multiple of 4, int4-aligned)
// meta[node] = { row_start_in_int4, rounds, bits(dinv), 0 }
__global__ __launch_bounds__(256) void k_bucket(const u32* __restrict__ tmp,
                                                const int* __restrict__ gcur,
                                                int4* __restrict__ meta,
                                                float* __restrict__ dinv,
                                                int* __restrict__ csr_src) {
    __shared__ int lcnt[128];
    __shared__ int sc[128];
    __shared__ int lcur[128];
    int tid = threadIdx.x, b = blockIdx.x;
    int lo = b * BCAPT, hi = lo + gcur[b];
    int pbase = b * CSTR;                       // int4-aligned (CSTR%4==0)
    if (tid < 128) lcnt[tid] = 0;
    __syncthreads();
    for (int e = lo + tid; e < hi; e += 256)
        atomicAdd(&lcnt[tmp[e] >> 20], 1);
    __syncthreads();
    int c  = (tid < 128) ? lcnt[tid] : 0;
    int c4 = (c + 4) & ~3;                      // edges + self, rounded up to 4
    if (tid < 128) sc[tid] = c4;
    __syncthreads();
    for (int off = 1; off < 128; off <<= 1) {
        int add = (tid < 128 && tid >= off) ? sc[tid - off] : 0;
        __syncthreads();
        if (tid < 128) sc[tid] += add;
        __syncthreads();
    }
    if (tid < 128) {
        int node = (b << 7) + tid;
        int excl = pbase + sc[tid] - c4;
        lcur[tid] = excl;
        if (node < N_NODES) {
            float di = rsqrtf((float)(c + 1));
            dinv[node] = di;
            int4 m; m.x = excl >> 2; m.y = c4 >> 2; m.z = __float_as_int(di); m.w = 0;
            meta[node] = m;
            csr_src[excl + c] = node;           // self contribution (Hb already *dinv)
            for (int k = c + 1; k < c4; ++k) csr_src[excl + k] = N_NODES;  // zero row
        }
    }
    __syncthreads();
    for (int e = lo + tid; e < hi; e += 256) {
        u32 pk = tmp[e];
        int slot = atomicAdd(&lcur[pk >> 20], 1);
        csr_src[slot] = (int)(pk & 0xFFFFFu);
    }
}

// ---- GEMM: Hb[M x 128](bf16) = (act(A) @ W) * dinv[row]
//   ABF16: A is packed bf16 (u32 pairs, 64/row); else f32.
//   FUSE:  act = leaky(A*scale+shift); scale/shift from NSPR-spread BN sums
//          (64B hot broadcast per column -> L2-resident, ~free).

template <bool FUSE, bool ABF16>
__global__ __launch_bounds__(256) void k_gemm(const void* __restrict__ Ap,
                                              const u16* __restrict__ Wz,
                                              const float* __restrict__ gsum,
                                              const float* __restrict__ gsq,
                                              const float* __restrict__ gam,
                                              const float* __restrict__ bet,
                                              const float* __restrict__ dinv,
                                              u16* __restrict__ Hb, int M) {
    __shared__ u16 wl[16384];  // 32 KB
    __shared__ float sLds[128], hLds[128];
    int tid = threadIdx.x;
    {
        const uint4* s4 = (const uint4*)Wz;
        uint4* d4 = (uint4*)wl;
        for (int i = tid; i < 2048; i += 256) d4[i] = s4[i];
    }
    if (FUSE && tid < 128) {
        float s = 0.f, s2 = 0.f;
#pragma unroll
        for (int k = 0; k < NSPR; ++k) { s += gsum[k * 128 + tid]; s2 += gsq[k * 128 + tid]; }
        float mean = s * (1.f / N_NODES);
        float var  = s2 * (1.f / N_NODES) - mean * mean;
        float rstd = rsqrtf(var + EPSBN);
        float sc = gam[tid] * rstd;
        sLds[tid] = sc;
        hLds[tid] = bet[tid] - mean * sc;
    }
    __syncthreads();
    int wave = tid >> 6, lane = tid & 63;
    long m0 = ((long)blockIdx.x * 4 + wave) * 16;
    if (m0 >= M) return;
    int mr = lane & 15, quad = lane >> 4;
    f32x4 acc[8] = {};
#pragma unroll
    for (int kc = 0; kc < 4; ++kc) {
        float av[8];
        if (ABF16) {
            const u32* arow = (const u32*)Ap + (size_t)(m0 + mr) * 64;
            uint4 aw = ((const uint4*)arow)[kc * 4 + quad];
            av[0] = bf_lo(aw.x); av[1] = bf_hi(aw.x);
            av[2] = bf_lo(aw.y); av[3] = bf_hi(aw.y);
            av[4] = bf_lo(aw.z); av[5] = bf_hi(aw.z);
            av[6] = bf_lo(aw.w); av[7] = bf_hi(aw.w);
        } else {
            const float* arow = (const float*)Ap + (size_t)(m0 + mr) * 128 + quad * 8;
            float4 a0 = *(const float4*)(arow + kc * 32);
            float4 a1 = *(const float4*)(arow + kc * 32 + 4);
            av[0] = a0.x; av[1] = a0.y; av[2] = a0.z; av[3] = a0.w;
            av[4] = a1.x; av[5] = a1.y; av[6] = a1.z; av[7] = a1.w;
        }
        if (FUSE) {
            int c = kc * 32 + quad * 8;
#pragma unroll
            for (int j = 0; j < 8; ++j) {
                float v = fmaf(av[j], sLds[c + j], hLds[c + j]);
                av[j] = v > 0.f ? v : v * SLOPE;
            }
        }
        bf16x8 af;
#pragma unroll
        for (int j = 0; j < 8; ++j) af[j] = (short)f2bf(av[j]);
        const u16* wb = wl + (kc * 4096 + lane * 8);  // fragment (kc,nt) at (kc*8+nt)*512
#pragma unroll
        for (int nt = 0; nt < 8; ++nt) {
            bf16x8 bf = *(const bf16x8*)(wb + nt * 512);
            acc[nt] = __builtin_amdgcn_mfma_f32_16x16x32_bf16(af, bf, acc[nt], 0, 0, 0);
        }
    }
    // C/D layout: col = lane&15, row = quad*4 + r ; scale row by dinv, store bf16
    float dr[4];
#pragma unroll
    for (int r = 0; r < 4; ++r) dr[r] = dinv[m0 + quad * 4 + r];
    u16* hb = Hb + (size_t)m0 * 128 + (lane & 15);
#pragma unroll
    for (int nt = 0; nt < 8; ++nt)
#pragma unroll
        for (int r = 0; r < 4; ++r)
            hb[(size_t)(quad * 4 + r) * 128 + nt * 16] = f2bf(acc[nt][r] * dr[r]);
}

// ---------------- aggregation ----------------
// One wave per node, 4 groups of 16 lanes. Padded CSR rows (multiple of 4,
// self folded in, zero-row pads): group g handles int4 slots r = g, g+4, ...
// Per round: one broadcast int4 index load + 4 row gathers + adds. No shfl,
// no tail masking, no weighted path.
// AGGb[d] = bf16( dinv[d] * sum_slots Hb[slot] )

__device__ __forceinline__ void add8(float* acc, uint4 w) {
    acc[0] += bf_lo(w.x); acc[1] += bf_hi(w.x);
    acc[2] += bf_lo(w.y); acc[3] += bf_hi(w.y);
    acc[4] += bf_lo(w.z); acc[5] += bf_hi(w.z);
    acc[6] += bf_lo(w.w); acc[7] += bf_hi(w.w);
}

__global__ __launch_bounds__(256) void k_agg(const uint4* __restrict__ Hb4,
                                             const int4* __restrict__ meta,
                                             const int4* __restrict__ csr4,
                                             u32* __restrict__ AGGb) {
    int wave = threadIdx.x >> 6, lane = threadIdx.x & 63;
    int node = blockIdx.x * 4 + wave;  // 25000*4 = 100000 exact
    int g = lane >> 4, f = lane & 15;
    int4 m = meta[node];               // wave-uniform 16B broadcast
    int s4 = m.x, rn = m.y;
    float di = __int_as_float(m.z);
    float acc[8] = {0.f, 0.f, 0.f, 0.f, 0.f, 0.f, 0.f, 0.f};
    for (int r = g; r < rn; r += 4) {
        int4 idx = csr4[s4 + r];       // 16 lanes same addr; 4 groups = 64B line
        uint4 a0 = Hb4[((size_t)idx.x << 4) + f];
        uint4 a1 = Hb4[((size_t)idx.y << 4) + f];
        uint4 a2 = Hb4[((size_t)idx.z << 4) + f];
        uint4 a3 = Hb4[((size_t)idx.w << 4) + f];
        add8(acc, a0); add8(acc, a1); add8(acc, a2); add8(acc, a3);
    }
#pragma unroll
    for (int i = 0; i < 8; ++i) {
        acc[i] += __shfl_xor(acc[i], 16);
        acc[i] += __shfl_xor(acc[i], 32);
    }
#pragma unroll
    for (int i = 0; i < 8; ++i) acc[i] *= di;
    if (g == 0) {                      // all groups hold the full sum; one writes
        u32 p0 = (u32)f2bf(acc[0]) | ((u32)f2bf(acc[1]) << 16);
        u32 p1 = (u32)f2bf(acc[2]) | ((u32)f2bf(acc[3]) << 16);
        u32 p2 = (u32)f2bf(acc[4]) | ((u32)f2bf(acc[5]) << 16);
        u32 p3 = (u32)f2bf(acc[6]) | ((u32)f2bf(acc[7]) << 16);
        uint4 o; o.x = p0; o.y = p1; o.z = p2; o.w = p3;
        ((uint4*)(AGGb + (size_t)node * 64))[f] = o;
    }
}

// ---------------- batch norm stats (bf16 AGG input) ----------------
// BW-optimal reduction: uint4 loads (16B/lane), grid-stride with i&15 == tid&15
// invariant (stride BNB*256 is a multiple of 16) -> each thread owns a fixed
// 8-column group; register accumulate -> shfl_xor(16/32) wave reduce -> LDS
// cross-wave reduce -> 128 atomics/block into NSPR-spread accumulators.
__global__ __launch_bounds__(256) void k_bnstats(const uint4* __restrict__ AGGb4,
                                                 float* __restrict__ gsum,
                                                 float* __restrict__ gsq) {
    __shared__ float red[512];         // 4 waves x 128 cols, reused for s then s2
    int tid = threadIdx.x;
    int wave = tid >> 6, lane = tid & 63;
    float s[8] = {0,0,0,0,0,0,0,0}, s2[8] = {0,0,0,0,0,0,0,0};
    for (long i = (long)blockIdx.x * 256 + tid; i < (long)N_NODES * 16;
         i += (long)BNB * 256) {
        uint4 w = AGGb4[i];
        float v;
        v = bf_lo(w.x); s[0] += v; s2[0] = fmaf(v, v, s2[0]);
        v = bf_hi(w.x); s[1] += v; s2[1] = fmaf(v, v, s2[1]);
        v = bf_lo(w.y); s[2] += v; s2[2] = fmaf(v, v, s2[2]);
        v = bf_hi(w.y); s[3] += v; s2[3] = fmaf(v, v, s2[3]);
        v = bf_lo(w.z); s[4] += v; s2[4] = fmaf(v, v, s2[4]);
        v = bf_hi(w.z); s[5] += v; s2[5] = fmaf(v, v, s2[5]);
        v = bf_lo(w.w); s[6] += v; s2[6] = fmaf(v, v, s2[6]);
        v = bf_hi(w.w); s[7] += v; s2[7] = fmaf(v, v, s2[7]);
    }
#pragma unroll
    for (int j = 0; j < 8; ++j) {
        s[j]  += __shfl_xor(s[j], 16);  s[j]  += __shfl_xor(s[j], 32);
        s2[j] += __shfl_xor(s2[j], 16); s2[j] += __shfl_xor(s2[j], 32);
    }
    // lanes 0..15 of each wave hold the wave total for cols lane*8+j
    if (lane < 16) {
#pragma unroll
        for (int j = 0; j < 8; ++j) red[wave * 128 + lane * 8 + j] = s[j];
    }
    __syncthreads();
    int spread = (blockIdx.x & (NSPR - 1)) * 128;
    if (tid < 128) {
        float v = red[tid] + red[128 + tid] + red[256 + tid] + red[384 + tid];
        atomicAdd(&gsum[spread + tid], v);
    }
    __syncthreads();
    if (lane < 16) {
#pragma unroll
        for (int j = 0; j < 8; ++j) red[wave * 128 + lane * 8 + j] = s2[j];
    }
    __syncthreads();
    if (tid < 128) {
        float v = red[tid] + red[128 + tid] + red[256 + tid] + red[384 + tid];
        atomicAdd(&gsq[spread + tid], v);
    }
}

// out = leaky(agg*scale + shift + x), f32 out; AGG bf16-packed, BN finalize
// inline from NSPR-spread sums. Grid-stride over 1.6M uint4.
__global__ __launch_bounds__(256) void k_ew2(const uint4* __restrict__ AGGb4,
                                             const float* __restrict__ gsum,
                                             const float* __restrict__ gsq,
                                             const float* __restrict__ gam,
                                             const float* __restrict__ bet,
                                             const float4* __restrict__ x4,
                                             float4* __restrict__ out4) {
    __shared__ float sLds[128], hLds[128];
    int tid = threadIdx.x;
    if (tid < 128) {
        float s = 0.f, s2 = 0.f;
#pragma unroll
        for (int k = 0; k < NSPR; ++k) { s += gsum[k * 128 + tid]; s2 += gsq[k * 128 + tid]; }
        float mean = s * (1.f / N_NODES);
        float var  = s2 * (1.f / N_NODES) - mean * mean;
        float rstd = rsqrtf(var + EPSBN);
        float sc = gam[tid] * rstd;
        sLds[tid] = sc;
        hLds[tid] = bet[tid] - mean * sc;
    }
    __syncthreads();
    for (long i = (long)blockIdx.x * 256 + tid; i < (long)N_NODES * 16; i += 2048 * 256) {
        int c8 = ((int)i & 15) * 8;
        uint4 w = AGGb4[i];
        float4 xa = x4[2 * i], xb = x4[2 * i + 1];
        float4 oa, ob;
        float v;
        v = fmaf(bf_lo(w.x), sLds[c8+0], hLds[c8+0]) + xa.x; oa.x = v > 0.f ? v : v * SLOPE;
        v = fmaf(bf_hi(w.x), sLds[c8+1], hLds[c8+1]) + xa.y; oa.y = v > 0.f ? v : v * SLOPE;
        v = fmaf(bf_lo(w.y), sLds[c8+2], hLds[c8+2]) + xa.z; oa.z = v > 0.f ? v : v * SLOPE;
        v = fmaf(bf_hi(w.y), sLds[c8+3], hLds[c8+3]) + xa.w; oa.w = v > 0.f ? v : v * SLOPE;
        v = fmaf(bf_lo(w.z), sLds[c8+4], hLds[c8+4]) + xb.x; ob.x = v > 0.f ? v : v * SLOPE;
        v = fmaf(bf_hi(w.z), sLds[c8+5], hLds[c8+5]) + xb.y; ob.y = v > 0.f ? v : v * SLOPE;
        v = fmaf(bf_lo(w.w), sLds[c8+6], hLds[c8+6]) + xb.z; ob.z = v > 0.f ? v : v * SLOPE;
        v = fmaf(bf_hi(w.w), sLds[c8+7], hLds[c8+7]) + xb.w; ob.w = v > 0.f ? v : v * SLOPE;
        out4[2 * i]     = oa;
        out4[2 * i + 1] = ob;
    }
}

// ---------------- launch ----------------

extern "C" void kernel_launch(void* const* d_in, const int* in_sizes, int n_in,
                              void* d_out, int out_size, void* d_ws, size_t ws_size,
                              hipStream_t stream) {
    const float* x   = (const float*)d_in[0];
    const int*   ei  = (const int*)d_in[1];
    const float* W1  = (const float*)d_in[2];
    const float* g1  = (const float*)d_in[4];
    const float* be1 = (const float*)d_in[5];
    const float* W2  = (const float*)d_in[6];
    const float* g2  = (const float*)d_in[8];
    const float* be2 = (const float*)d_in[9];
    const int* src = ei;
    const int* dst = ei + N_EDGES;

    float* out = (float*)d_out;
    u16*   Hb  = (u16*)d_out;  // bf16 H (rows 0..N_NODES incl zero-row) lives in d_out

    char* p = (char*)d_ws;
    u32*   aggb    = (u32*)p;   p += (size_t)N_NODES * 64 * 4;   // 25.6 MB bf16 AGG
    u32*   tmp     = aggb;      // tmp (NBUCK*BCAPT*4 = 8.0 MB) overlays aggb:
                                // dead before first k_agg write
    int*   csr_src = (int*)p;   p += (size_t)NBUCK * CSTR * 4;   // 9.6 MB padded CSR
    int*   gcur    = (int*)p;   p += 1024 * 4;                   // bucket cursors
    int4*  meta    = (int4*)p;  p += (size_t)100096 * 16;        // 1.6 MB
    float* dinv    = (float*)p; p += (size_t)100096 * 4;
    float* stats   = (float*)p; p += 8192 * 4;                   // 4x 16-spread arrays
    u16*   wz1     = (u16*)p;   p += 16384 * 2;
    u16*   wz2     = (u16*)p;   p += 16384 * 2;

    float* gs1 = stats,        *gq1 = stats + 2048;
    float* gs2 = stats + 4096, *gq2 = stats + 6144;

    // setup: init/swz -> fused hist+claim+scatter -> per-bucket padded-CSR build
    k_init<<<48, 256, 0, stream>>>(W1, W2, wz1, wz2, stats,
                                   (u32*)Hb + (size_t)N_NODES * 64, gcur);
    k_part2<<<PBLK, 256, 0, stream>>>(src, dst, gcur, tmp);
    k_bucket<<<NBUCK, 256, 0, stream>>>(tmp, gcur, meta, dinv, csr_src);

    // layer 1:  Hb1 = (x@W1)*dinv -> d_out (bf16),  AGG1(bf16) -> aggb
    k_gemm<false, false><<<1563, 256, 0, stream>>>(x, wz1, nullptr, nullptr, nullptr,
                                                   nullptr, dinv, Hb, N_NODES);
    k_agg<<<25000, 256, 0, stream>>>((const uint4*)Hb, meta, (const int4*)csr_src, aggb);
    k_bnstats<<<BNB, 256, 0, stream>>>((const uint4*)aggb, gs1, gq1);

    // layer 2:  Hb2 = (leaky(BN1(AGG1))@W2)*dinv -> d_out;  AGG2(bf16) -> aggb
    k_gemm<true, true><<<1563, 256, 0, stream>>>(aggb, wz2, gs1, gq1, g1, be1,
                                                 dinv, Hb, N_NODES);
    k_agg<<<25000, 256, 0, stream>>>((const uint4*)Hb, meta, (const int4*)csr_src, aggb);
    k_bnstats<<<BNB, 256, 0, stream>>>((const uint4*)aggb, gs2, gq2);

    // epilogue: BN2 finalize inline + residual + leaky
    k_ew2<<<2048, 256, 0, stream>>>((const uint4*)aggb, gs2, gq2, g2, be2,
                                    (const float4*)x, (float4*)out);
}